// Round 6
// baseline (62.555 us; speedup 1.0000x reference)
//
#include <hip/hip_runtime.h>

// GraphConv: out[b,i,c] = relu( VW[b,0,i,c] + sum_{j,l} A[b,i,j,l] * VW[b,l+1,j,c] )
// VW[b,l,j,c] = sum_f V[b,j,f] h[l,c,f]
// K2 key fact: flattening A's (j,l) axes gives contiguous K=4096 with k=j*4+l.
// R6: K2 tile 64i x 256c, 256 thr (4 waves of 64i x 64c), KT=8 -> grid 1024 =
// 4 blocks/CU (LDS 40KB) for barrier-stall coverage. b<->XCD alignment in all
// kernels: partials/W2t/VW0 stay in the producing XCD's L2.

typedef float          f32x4  __attribute__((ext_vector_type(4)));
typedef __bf16         bf16x8 __attribute__((ext_vector_type(8)));
typedef unsigned short u16x4  __attribute__((ext_vector_type(4)));
typedef unsigned int   u32x4  __attribute__((ext_vector_type(4)));

#define DEV __device__ __forceinline__

DEV void glds16(const void* g, void* l) {
  __builtin_amdgcn_global_load_lds((const __attribute__((address_space(1))) void*)g,
                                   (__attribute__((address_space(3))) void*)l,
                                   16, 0, 0);
}

DEV void cvt8(__bf16* d, f32x4 u, f32x4 v) {
  bf16x8 o;
  o[0]=(__bf16)u[0]; o[1]=(__bf16)u[1]; o[2]=(__bf16)u[2]; o[3]=(__bf16)u[3];
  o[4]=(__bf16)v[0]; o[5]=(__bf16)v[1]; o[6]=(__bf16)v[2]; o[7]=(__bf16)v[3];
  *(bf16x8*)d = o;
}

DEV unsigned short bfbits(float x) {
  return __builtin_bit_cast(unsigned short, (__bf16)x);
}

// ---------------------------------------------------------------------------
// K1: VW projection.  Per block: (b, j-tile 128, c-tile 64), all 5 l.
// Writes W2t[b][c][j*4 + (l-1)] bf16 and VW0[b][j][c] f32.
// R6: only change is b<->XCD block swizzle.
// ---------------------------------------------------------------------------
__global__ __launch_bounds__(512, 2)
void k1_vw(const float* __restrict__ Vg, const float* __restrict__ Hg,
           unsigned short* __restrict__ W2t, float* __restrict__ VW0)
{
  __shared__ __attribute__((aligned(16))) __bf16 Vs[2][128*64];
  __shared__ __attribute__((aligned(16))) __bf16 Hs[2][320*64];

  const int tid  = threadIdx.x;
  const int lane = tid & 63;
  const int wid  = tid >> 6;
  const int wj   = wid >> 1;
  const int wc   = wid & 1;
  const int li   = lane & 15;
  const int lg   = lane >> 4;

  // b == XCD id
  const int p    = blockIdx.x;       // 256 blocks
  const int b    = p & 7;
  const int rest = p >> 3;           // 0..31
  const int ct   = rest & 3;
  const int jt   = rest >> 2;
  const int j0   = jt * 128;
  const int c0   = ct * 64;

  const float* sptr[7];
  int sdst[7];
#pragma unroll
  for (int r = 0; r < 2; ++r) {
    int n = r*512 + tid, row = n >> 3, q = n & 7;
    sptr[r] = Vg + (size_t)(b*1024 + j0 + row)*256 + q*8;
    sdst[r] = row*64 + ((q ^ (row & 7))*8);
  }
#pragma unroll
  for (int r = 0; r < 5; ++r) {
    int n = r*512 + tid, row = n >> 3, q = n & 7;
    int l = row >> 6, cl = row & 63;
    sptr[2+r] = Hg + (size_t)(l*256 + c0 + cl)*256 + q*8;
    sdst[2+r] = row*64 + ((q ^ (row & 7))*8);
  }

  f32x4 acc[5][2][2];
#pragma unroll
  for (int l=0;l<5;l++)
#pragma unroll
    for (int x=0;x<2;x++)
#pragma unroll
      for (int y=0;y<2;y++) acc[l][x][y] = (f32x4){0.f,0.f,0.f,0.f};

  {
    f32x4 sa[14];
#pragma unroll
    for (int i=0;i<7;i++) { sa[2*i] = *(const f32x4*)(sptr[i]); sa[2*i+1] = *(const f32x4*)(sptr[i]+4); }
#pragma unroll
    for (int i=0;i<7;i++) {
      __bf16* d = (i < 2) ? &Vs[0][sdst[i]] : &Hs[0][sdst[i]];
      cvt8(d, sa[2*i], sa[2*i+1]);
    }
  }
  __syncthreads();

  int cur = 0;
#pragma unroll 1
  for (int t = 0; t < 4; ++t) {
    const int nxt = cur ^ 1;
    f32x4 sa[14];
    if (t < 3) {
      const int ko = (t+1)*64;
#pragma unroll
      for (int i=0;i<7;i++) { sa[2*i] = *(const f32x4*)(sptr[i]+ko); sa[2*i+1] = *(const f32x4*)(sptr[i]+ko+4); }
    }
    const __bf16* Vsc = &Vs[cur][0];
    const __bf16* Hsc = &Hs[cur][0];
#pragma unroll
    for (int ks = 0; ks < 2; ++ks) {
      bf16x8 hf[10], vf[2];
#pragma unroll
      for (int l=0;l<5;l++)
#pragma unroll
        for (int cm=0;cm<2;cm++) {
          int row = l*64 + wc*32 + cm*16 + li;
          int ch  = (ks*4 + lg) ^ (row & 7);
          hf[l*2+cm] = *(const bf16x8*)(Hsc + row*64 + ch*8);
        }
#pragma unroll
      for (int jn=0;jn<2;jn++) {
        int row = wj*32 + jn*16 + li;
        int ch  = (ks*4 + lg) ^ (row & 7);
        vf[jn] = *(const bf16x8*)(Vsc + row*64 + ch*8);
      }
#pragma unroll
      for (int l=0;l<5;l++)
#pragma unroll
        for (int cm=0;cm<2;cm++)
#pragma unroll
          for (int jn=0;jn<2;jn++)
            acc[l][cm][jn] = __builtin_amdgcn_mfma_f32_16x16x32_bf16(
                hf[l*2+cm], vf[jn], acc[l][cm][jn], 0, 0, 0);
    }
    if (t < 3) {
#pragma unroll
      for (int i=0;i<7;i++) {
        __bf16* d = (i < 2) ? &Vs[nxt][sdst[i]] : &Hs[nxt][sdst[i]];
        cvt8(d, sa[2*i], sa[2*i+1]);
      }
    }
    __syncthreads();
    cur = nxt;
  }

#pragma unroll
  for (int cm=0;cm<2;cm++)
#pragma unroll
    for (int r=0;r<4;r++) {
      const int c = c0 + wc*32 + cm*16 + lg*4 + r;
#pragma unroll
      for (int jn=0;jn<2;jn++) {
        const int j = j0 + wj*32 + jn*16 + li;
        u16x4 pk;
        pk[0] = bfbits(acc[1][cm][jn][r]);
        pk[1] = bfbits(acc[2][cm][jn][r]);
        pk[2] = bfbits(acc[3][cm][jn][r]);
        pk[3] = bfbits(acc[4][cm][jn][r]);
        *(u16x4*)(W2t + (size_t)(b*256 + c)*4096 + (size_t)j*4) = pk;
        VW0[(size_t)(b*1024 + j)*256 + c] = acc[0][cm][jn][r];
      }
    }
}

// ---------------------------------------------------------------------------
// K2: partial[kt][b][i][c] = sum_{k in chunk} A[b][i][k] * W2t[b][c][k]
// Tile 64(i) x 256(c, full), k-split 8. Block: 256 thr = 4 waves (c 64-strips),
// wave = 64i x 64c = 4x4 frags, 16 MFMA/step. K-step 32, NSTEP=16.
// A: reg-stage f32->bf16 (1 chunk/thread). B: global_load_lds x4 rounds.
// LDS 40KB dbuf -> 4 blocks/CU x 4 waves = 4 waves/SIMD, grid 1024.
// b == XCD id (A/W2t/partials L2-local).
// Swizzle: LDS chunk position q holds GLOBAL chunk q^s, s=(row>>1)&3.
// ---------------------------------------------------------------------------
__global__ __launch_bounds__(256, 4)
void k2_gemm(const float* __restrict__ Ag, const unsigned short* __restrict__ W2t,
             unsigned short* __restrict__ part)
{
  __shared__ __attribute__((aligned(16))) __bf16 As[2][64*32];   // 2 x 4 KB
  __shared__ __attribute__((aligned(16))) __bf16 Bs[2][256*32];  // 2 x 16 KB

  constexpr int KT    = 8;
  constexpr int KCH   = 4096 / KT;   // 512
  constexpr int NSTEP = KCH / 32;    // 16

  const int tid  = threadIdx.x;
  const int lane = tid & 63;
  const int wc   = tid >> 6;   // 0..3 (c 64-strips)
  const int li   = lane & 15;
  const int lg   = lane >> 4;

  // b == XCD id
  const int p    = blockIdx.x;       // 1024 blocks
  const int b    = p & 7;
  const int rest = p >> 3;           // 0..127
  const int kt   = rest & 7;
  const int it   = rest >> 3;        // 0..15

  const int i0 = it*64, k0 = kt*KCH;

  // A staging: 1 chunk/thread. chunk n=tid: row=n>>2, q=n&3.
  const int arow = tid >> 2, aq = tid & 3;
  const float* asrc = Ag + (size_t)(b*1024 + i0 + arow)*4096 + k0 + aq*8;
  const int ad = arow*32 + ((aq ^ ((arow >> 1) & 3))*8);

  // B staging via glds: 4 rounds. chunk n=r*256+tid: row=n>>2, q=n&3.
  const unsigned short* bsrc[4];
  int bd[4];
#pragma unroll
  for (int r = 0; r < 4; ++r) {
    int n = r*256 + tid, row = n >> 2, q = n & 3;
    bsrc[r] = W2t + (size_t)(b*256 + row)*4096 + k0 + ((q ^ ((row>>1)&3))*8);
    bd[r]   = r*2048 + wc*512;   // wave-uniform base; HW adds lane*16B
  }

  f32x4 acc[4][4];
#pragma unroll
  for (int m=0;m<4;m++)
#pragma unroll
    for (int n=0;n<4;n++) acc[m][n] = (f32x4){0.f,0.f,0.f,0.f};

  // prologue: stage step 0 into buf 0
  {
    f32x4 a0 = *(const f32x4*)asrc, a1 = *(const f32x4*)(asrc+4);
#pragma unroll
    for (int r=0;r<4;r++) glds16(bsrc[r], &Bs[0][bd[r]]);
    cvt8(&As[0][ad], a0, a1);
  }
  __syncthreads();

  int cur = 0;
#pragma unroll 1
  for (int t = 0; t < NSTEP; ++t) {
    const int nxt = cur ^ 1;
    f32x4 a0, a1;
    if (t < NSTEP-1) {
      const int o = (t+1)*32;
      a0 = *(const f32x4*)(asrc + o);
      a1 = *(const f32x4*)(asrc + o + 4);
#pragma unroll
      for (int r=0;r<4;r++) glds16(bsrc[r] + o, &Bs[nxt][bd[r]]);
    }
    {
      bf16x8 af[4], bfv[4];
#pragma unroll
      for (int m=0;m<4;m++) {
        int row = m*16 + li;
        int ch  = lg ^ ((row >> 1) & 3);
        af[m] = *(const bf16x8*)(&As[cur][row*32 + ch*8]);
      }
#pragma unroll
      for (int n=0;n<4;n++) {
        int row = wc*64 + n*16 + li;
        int ch  = lg ^ ((row >> 1) & 3);
        bfv[n] = *(const bf16x8*)(&Bs[cur][row*32 + ch*8]);
      }
#pragma unroll
      for (int m=0;m<4;m++)
#pragma unroll
        for (int n=0;n<4;n++)
          acc[m][n] = __builtin_amdgcn_mfma_f32_16x16x32_bf16(af[m], bfv[n], acc[m][n], 0, 0, 0);
    }
    if (t < NSTEP-1) cvt8(&As[nxt][ad], a0, a1);
    __syncthreads();
    cur = nxt;
  }

  // epilogue -> bf16 partial plane
  unsigned short* pb = part + (size_t)kt*2097152u + (size_t)(b*1024 + i0)*256;
#pragma unroll
  for (int m=0;m<4;m++)
#pragma unroll
    for (int r=0;r<4;r++) {
      const int il = m*16 + lg*4 + r;
#pragma unroll
      for (int n=0;n<4;n++) {
        const int cl = wc*64 + n*16 + li;
        pb[(size_t)il*256 + cl] = bfbits(acc[m][n][r]);
      }
    }
}

// ---------------------------------------------------------------------------
// K3: out = relu(VW0 + sum_{kt} partial[kt]), 8 elems/thread.
// b == XCD id: partials for batch b were produced on XCD b -> L2-local reads.
// ---------------------------------------------------------------------------
__global__ __launch_bounds__(256)
void k3_reduce(const unsigned short* __restrict__ part, const float* __restrict__ VW0,
               float* __restrict__ out)
{
  const int p   = blockIdx.x;        // 1024 blocks
  const int b   = p & 7;
  const int off = p >> 3;            // 0..127
  const size_t i8 = (size_t)b*262144u + (size_t)off*2048u + (size_t)threadIdx.x*8;
  f32x4 s0 = *(const f32x4*)(VW0 + i8);
  f32x4 s1 = *(const f32x4*)(VW0 + i8 + 4);
#pragma unroll
  for (int q=0;q<8;q++) {
    u32x4 u = *(const u32x4*)(part + (size_t)q*2097152u + i8);
    s0[0] += __uint_as_float(u[0] << 16);  s0[1] += __uint_as_float(u[0] & 0xffff0000u);
    s0[2] += __uint_as_float(u[1] << 16);  s0[3] += __uint_as_float(u[1] & 0xffff0000u);
    s1[0] += __uint_as_float(u[2] << 16);  s1[1] += __uint_as_float(u[2] & 0xffff0000u);
    s1[2] += __uint_as_float(u[3] << 16);  s1[3] += __uint_as_float(u[3] & 0xffff0000u);
  }
#pragma unroll
  for (int e=0;e<4;e++){ s0[e] = fmaxf(s0[e],0.f); s1[e] = fmaxf(s1[e],0.f); }
  *(f32x4*)(out + i8)     = s0;
  *(f32x4*)(out + i8 + 4) = s1;
}

// ---------------------------------------------------------------------------
extern "C" void kernel_launch(void* const* d_in, const int* in_sizes, int n_in,
                              void* d_out, int out_size, void* d_ws, size_t ws_size,
                              hipStream_t stream) {
  const float* Vg = (const float*)d_in[0];   // (8,1024,256) f32
  const float* Ag = (const float*)d_in[1];   // (8,1024,1024,4) f32
  const float* Hg = (const float*)d_in[2];   // (5,256,256) f32
  float* out = (float*)d_out;                // (8,1024,256) f32

  // ws: W2t bf16 16MB | VW0 f32 8MB | partials bf16 32MB  (= 56MB)
  if (ws_size < 58720256u) return;
  char* ws = (char*)d_ws;
  unsigned short* W2t  = (unsigned short*)(ws);
  float*          VW0  = (float*)(ws + 16777216u);
  unsigned short* part = (unsigned short*)(ws + 16777216u + 8388608u);

  k1_vw    <<<dim3(256),  dim3(512), 0, stream>>>(Vg, Hg, W2t, VW0);
  k2_gemm  <<<dim3(1024), dim3(256), 0, stream>>>(Ag, W2t, part);
  k3_reduce<<<dim3(1024), dim3(256), 0, stream>>>(part, VW0, out);
}

// Round 7
// 51.456 us; speedup vs baseline: 1.2157x; 1.2157x over previous
//
#include <hip/hip_runtime.h>

// GraphConv: out[b,i,c] = relu( VW[b,0,i,c] + sum_{j,l} A[b,i,j,l] * VW[b,l+1,j,c] )
// VW[b,l,j,c] = sum_f V[b,j,f] h[l,c,f]
// K2 key fact: flattening A's (j,l) axes gives contiguous K=4096 with k=j*4+l.
// R7 K2: BM=128i x BN=256c x BK=64, KT=4, 8 waves. Both operands reg-staged in
// alternating 8-load banks; raw s_barrier + lgkmcnt(0) only (no __syncthreads,
// so the compiler's dependency waits give counted vmcnt(8) -- never a drain to
// 0 in the loop). One barrier per BK=64. Full XOR swizzle chunk^(row&7).

typedef float          f32x4  __attribute__((ext_vector_type(4)));
typedef __bf16         bf16x8 __attribute__((ext_vector_type(8)));
typedef unsigned short u16x4  __attribute__((ext_vector_type(4)));
typedef unsigned int   u32x4  __attribute__((ext_vector_type(4)));

#define DEV __device__ __forceinline__

DEV void glds16(const void* g, void* l) {
  __builtin_amdgcn_global_load_lds((const __attribute__((address_space(1))) void*)g,
                                   (__attribute__((address_space(3))) void*)l,
                                   16, 0, 0);
}

DEV void cvt8(__bf16* d, f32x4 u, f32x4 v) {
  bf16x8 o;
  o[0]=(__bf16)u[0]; o[1]=(__bf16)u[1]; o[2]=(__bf16)u[2]; o[3]=(__bf16)u[3];
  o[4]=(__bf16)v[0]; o[5]=(__bf16)v[1]; o[6]=(__bf16)v[2]; o[7]=(__bf16)v[3];
  *(bf16x8*)d = o;
}

DEV bf16x8 cvt8r(f32x4 u, f32x4 v) {
  bf16x8 o;
  o[0]=(__bf16)u[0]; o[1]=(__bf16)u[1]; o[2]=(__bf16)u[2]; o[3]=(__bf16)u[3];
  o[4]=(__bf16)v[0]; o[5]=(__bf16)v[1]; o[6]=(__bf16)v[2]; o[7]=(__bf16)v[3];
  return o;
}

DEV unsigned short bfbits(float x) {
  return __builtin_bit_cast(unsigned short, (__bf16)x);
}

// ---------------------------------------------------------------------------
// K1: VW projection.  Per block: (b, j-tile 128, c-tile 64), all 5 l.
// Writes W2t[b][c][j*4 + (l-1)] bf16 and VW0[b][j][c] f32.  (unchanged)
// ---------------------------------------------------------------------------
__global__ __launch_bounds__(512, 2)
void k1_vw(const float* __restrict__ Vg, const float* __restrict__ Hg,
           unsigned short* __restrict__ W2t, float* __restrict__ VW0)
{
  __shared__ __attribute__((aligned(16))) __bf16 Vs[2][128*64];
  __shared__ __attribute__((aligned(16))) __bf16 Hs[2][320*64];

  const int tid  = threadIdx.x;
  const int lane = tid & 63;
  const int wid  = tid >> 6;
  const int wj   = wid >> 1;
  const int wc   = wid & 1;
  const int li   = lane & 15;
  const int lg   = lane >> 4;

  const int p    = blockIdx.x;       // 256 blocks
  const int b    = p & 7;
  const int rest = p >> 3;
  const int ct   = rest & 3;
  const int jt   = rest >> 2;
  const int j0   = jt * 128;
  const int c0   = ct * 64;

  const float* sptr[7];
  int sdst[7];
#pragma unroll
  for (int r = 0; r < 2; ++r) {
    int n = r*512 + tid, row = n >> 3, q = n & 7;
    sptr[r] = Vg + (size_t)(b*1024 + j0 + row)*256 + q*8;
    sdst[r] = row*64 + ((q ^ (row & 7))*8);
  }
#pragma unroll
  for (int r = 0; r < 5; ++r) {
    int n = r*512 + tid, row = n >> 3, q = n & 7;
    int l = row >> 6, cl = row & 63;
    sptr[2+r] = Hg + (size_t)(l*256 + c0 + cl)*256 + q*8;
    sdst[2+r] = row*64 + ((q ^ (row & 7))*8);
  }

  f32x4 acc[5][2][2];
#pragma unroll
  for (int l=0;l<5;l++)
#pragma unroll
    for (int x=0;x<2;x++)
#pragma unroll
      for (int y=0;y<2;y++) acc[l][x][y] = (f32x4){0.f,0.f,0.f,0.f};

  {
    f32x4 sa[14];
#pragma unroll
    for (int i=0;i<7;i++) { sa[2*i] = *(const f32x4*)(sptr[i]); sa[2*i+1] = *(const f32x4*)(sptr[i]+4); }
#pragma unroll
    for (int i=0;i<7;i++) {
      __bf16* d = (i < 2) ? &Vs[0][sdst[i]] : &Hs[0][sdst[i]];
      cvt8(d, sa[2*i], sa[2*i+1]);
    }
  }
  __syncthreads();

  int cur = 0;
#pragma unroll 1
  for (int t = 0; t < 4; ++t) {
    const int nxt = cur ^ 1;
    f32x4 sa[14];
    if (t < 3) {
      const int ko = (t+1)*64;
#pragma unroll
      for (int i=0;i<7;i++) { sa[2*i] = *(const f32x4*)(sptr[i]+ko); sa[2*i+1] = *(const f32x4*)(sptr[i]+ko+4); }
    }
    const __bf16* Vsc = &Vs[cur][0];
    const __bf16* Hsc = &Hs[cur][0];
#pragma unroll
    for (int ks = 0; ks < 2; ++ks) {
      bf16x8 hf[10], vf[2];
#pragma unroll
      for (int l=0;l<5;l++)
#pragma unroll
        for (int cm=0;cm<2;cm++) {
          int row = l*64 + wc*32 + cm*16 + li;
          int ch  = (ks*4 + lg) ^ (row & 7);
          hf[l*2+cm] = *(const bf16x8*)(Hsc + row*64 + ch*8);
        }
#pragma unroll
      for (int jn=0;jn<2;jn++) {
        int row = wj*32 + jn*16 + li;
        int ch  = (ks*4 + lg) ^ (row & 7);
        vf[jn] = *(const bf16x8*)(Vsc + row*64 + ch*8);
      }
#pragma unroll
      for (int l=0;l<5;l++)
#pragma unroll
        for (int cm=0;cm<2;cm++)
#pragma unroll
          for (int jn=0;jn<2;jn++)
            acc[l][cm][jn] = __builtin_amdgcn_mfma_f32_16x16x32_bf16(
                hf[l*2+cm], vf[jn], acc[l][cm][jn], 0, 0, 0);
    }
    if (t < 3) {
#pragma unroll
      for (int i=0;i<7;i++) {
        __bf16* d = (i < 2) ? &Vs[nxt][sdst[i]] : &Hs[nxt][sdst[i]];
        cvt8(d, sa[2*i], sa[2*i+1]);
      }
    }
    __syncthreads();
    cur = nxt;
  }

#pragma unroll
  for (int cm=0;cm<2;cm++)
#pragma unroll
    for (int r=0;r<4;r++) {
      const int c = c0 + wc*32 + cm*16 + lg*4 + r;
#pragma unroll
      for (int jn=0;jn<2;jn++) {
        const int j = j0 + wj*32 + jn*16 + li;
        u16x4 pk;
        pk[0] = bfbits(acc[1][cm][jn][r]);
        pk[1] = bfbits(acc[2][cm][jn][r]);
        pk[2] = bfbits(acc[3][cm][jn][r]);
        pk[3] = bfbits(acc[4][cm][jn][r]);
        *(u16x4*)(W2t + (size_t)(b*256 + c)*4096 + (size_t)j*4) = pk;
        VW0[(size_t)(b*1024 + j)*256 + c] = acc[0][cm][jn][r];
      }
    }
}

// ---------------------------------------------------------------------------
// K2 (R7). partial[kt][b][i][c] = sum_{k in chunk} A[b][i][k] * W2t[b][c][k]
// BM=128, BN=256, BK=64, KT=4. 512 thr = 8 waves (wi 0..1 x wc 0..3),
// wave = 64i x 64c = 4x4 frags, 32 MFMA per BK-tile.
// Pipeline: half-iter T = { load regs for tile T+2 (8 loads), ds_write tile
// T+1 (regs->LDS, compiler emits counted vmcnt(8)), compute tile T (2 kk x
// 2 n-pair phases), lgkmcnt(0), s_barrier }.  No vmcnt(0) anywhere in loop.
// LDS: A[2][128*64] 16KB*2 + B[2][256*64] 32KB*2 = 96KB -> 1 blk/CU, 2 w/SIMD.
// Swizzle both sides: LDS chunk position = global_chunk ^ (row&7).
// ---------------------------------------------------------------------------
#define K2_FENCE() do {                                          \
    asm volatile("s_waitcnt lgkmcnt(0)" ::: "memory");           \
    __builtin_amdgcn_sched_barrier(0);                           \
    __builtin_amdgcn_s_barrier();                                \
    __builtin_amdgcn_sched_barrier(0);                           \
  } while (0)

__global__ __launch_bounds__(512, 2)
void k2_gemm(const float* __restrict__ Ag, const unsigned short* __restrict__ W2t,
             unsigned short* __restrict__ part)
{
  __shared__ __attribute__((aligned(16))) __bf16 As[2][128*64];  // 2 x 16 KB
  __shared__ __attribute__((aligned(16))) __bf16 Bs[2][256*64];  // 2 x 32 KB

  const int tid  = threadIdx.x;
  const int lane = tid & 63;
  const int wid  = tid >> 6;   // 0..7
  const int wi   = wid >> 2;   // 0..1 (i 64-strips)
  const int wc   = wid & 3;    // 0..3 (c 64-strips)
  const int li   = lane & 15;
  const int lg   = lane >> 4;
  const int ls   = li & 7;     // read-side swizzle key (= row&7 for all frag rows)

  const int p    = blockIdx.x;       // 256 blocks; b == XCD id
  const int b    = p & 7;
  const int rest = p >> 3;           // 0..31
  const int kt   = rest & 3;
  const int it   = rest >> 2;        // 0..7

  const int i0 = it*128;
  const int k0 = kt*1024;           // f32/bf16 element offset in K

  // ---- A staging map: thread -> (row ar, global chunks {aq, aq+4}) ----
  const int ar = tid >> 2, aq = tid & 3, as_ = ar & 7;
  const float* asrc = Ag + (size_t)(b*1024 + i0 + ar)*4096 + k0;
  const int awo0 = ar*64 + ((aq     ^ as_)*8);   // LDS elem offsets
  const int awo1 = ar*64 + (((aq+4) ^ as_)*8);
  const int ago0 = aq*8;        // global f32 offset within tile (chunk aq)
  const int ago1 = aq*8 + 32;   // chunk aq+4

  // ---- B staging map: thread -> (row br, global chunks {4h..4h+3}) ----
  const int br = tid >> 1, h = tid & 1, bs_ = br & 7;
  const unsigned short* bsrc = W2t + (size_t)(b*256 + br)*4096 + k0;
  int bwo[4], bgo[4];
#pragma unroll
  for (int j=0;j<4;j++) {
    bwo[j] = br*64 + (((4*h+j) ^ bs_)*8);
    bgo[j] = (4*h+j)*8;
  }

  f32x4 acc[4][4];
#pragma unroll
  for (int m=0;m<4;m++)
#pragma unroll
    for (int n=0;n<4;n++) acc[m][n] = (f32x4){0.f,0.f,0.f,0.f};

  // staging register banks (E = even tiles, O = odd tiles)
  f32x4 aE0,aE1,aE2,aE3, aO0,aO1,aO2,aO3;
  u32x4 bE0,bE1,bE2,bE3, bO0,bO1,bO2,bO3;

#define K2_LOAD(S, t) do {                                                   \
    const float* _ap = asrc + (t)*64;                                        \
    a##S##0 = *(const f32x4*)(_ap + ago0);                                   \
    a##S##1 = *(const f32x4*)(_ap + ago0 + 4);                               \
    a##S##2 = *(const f32x4*)(_ap + ago1);                                   \
    a##S##3 = *(const f32x4*)(_ap + ago1 + 4);                               \
    const unsigned short* _bp = bsrc + (t)*64;                               \
    b##S##0 = *(const u32x4*)(_bp + bgo[0]);                                 \
    b##S##1 = *(const u32x4*)(_bp + bgo[1]);                                 \
    b##S##2 = *(const u32x4*)(_bp + bgo[2]);                                 \
    b##S##3 = *(const u32x4*)(_bp + bgo[3]);                                 \
  } while (0)

#define K2_DSW(S, X) do {                                                    \
    *(bf16x8*)(&As[X][awo0]) = cvt8r(a##S##0, a##S##1);                      \
    *(bf16x8*)(&As[X][awo1]) = cvt8r(a##S##2, a##S##3);                      \
    *(u32x4*)(&Bs[X][bwo[0]]) = b##S##0;                                     \
    *(u32x4*)(&Bs[X][bwo[1]]) = b##S##1;                                     \
    *(u32x4*)(&Bs[X][bwo[2]]) = b##S##2;                                     \
    *(u32x4*)(&Bs[X][bwo[3]]) = b##S##3;                                     \
  } while (0)

#define K2_COMP(X) do {                                                      \
    _Pragma("unroll")                                                        \
    for (int kk=0;kk<2;kk++) {                                               \
      bf16x8 af[4];                                                          \
      _Pragma("unroll")                                                      \
      for (int m=0;m<4;m++) {                                                \
        int row = wi*64 + m*16 + li;                                         \
        af[m] = *(const bf16x8*)(&As[X][row*64 + (((kk*4+lg) ^ ls)*8)]);     \
      }                                                                      \
      _Pragma("unroll")                                                      \
      for (int np=0;np<2;np++) {                                             \
        bf16x8 bf0, bf1;                                                     \
        {                                                                    \
          int row0 = wc*64 + (np*2  )*16 + li;                               \
          int row1 = wc*64 + (np*2+1)*16 + li;                               \
          bf0 = *(const bf16x8*)(&Bs[X][row0*64 + (((kk*4+lg) ^ ls)*8)]);    \
          bf1 = *(const bf16x8*)(&Bs[X][row1*64 + (((kk*4+lg) ^ ls)*8)]);    \
        }                                                                    \
        __builtin_amdgcn_s_setprio(1);                                       \
        _Pragma("unroll")                                                    \
        for (int m=0;m<4;m++) {                                              \
          acc[m][np*2  ] = __builtin_amdgcn_mfma_f32_16x16x32_bf16(          \
              af[m], bf0, acc[m][np*2  ], 0, 0, 0);                          \
          acc[m][np*2+1] = __builtin_amdgcn_mfma_f32_16x16x32_bf16(          \
              af[m], bf1, acc[m][np*2+1], 0, 0, 0);                          \
        }                                                                    \
        __builtin_amdgcn_s_setprio(0);                                       \
      }                                                                      \
    }                                                                        \
  } while (0)

  // ---- prologue: tiles 0,1 -> regs; tile 0 -> LDS buf0 ----
  K2_LOAD(E, 0);
  K2_LOAD(O, 1);
  K2_DSW(E, 0);
  K2_FENCE();

  // ---- main loop: u=0..6, half-iters T=2u (buf0), T=2u+1 (buf1) ----
#pragma unroll 1
  for (int u = 0; u < 7; ++u) {
    K2_LOAD(E, 2*u+2);
    K2_DSW(O, 1);          // tile 2u+1 -> buf1 (vmcnt counted: 8 newer loads)
    K2_COMP(0);            // tile 2u from buf0
    K2_FENCE();

    K2_LOAD(O, 2*u+3);
    K2_DSW(E, 0);          // tile 2u+2 -> buf0
    K2_COMP(1);            // tile 2u+1 from buf1
    K2_FENCE();
  }
  // computed 0..13; buf0 holds 14; O-regs hold 15
  K2_DSW(O, 1);            // tile 15 -> buf1
  K2_COMP(0);              // tile 14
  K2_FENCE();
  K2_COMP(1);              // tile 15

#undef K2_LOAD
#undef K2_DSW
#undef K2_COMP

  // ---- epilogue -> bf16 partial plane ----
  unsigned short* pb = part + (size_t)kt*2097152u + (size_t)(b*1024 + i0)*256;
#pragma unroll
  for (int m=0;m<4;m++)
#pragma unroll
    for (int r=0;r<4;r++) {
      const int il = wi*64 + m*16 + lg*4 + r;
#pragma unroll
      for (int n=0;n<4;n++) {
        const int cl = wc*64 + n*16 + li;
        pb[(size_t)il*256 + cl] = bfbits(acc[m][n][r]);
      }
    }
}

// ---------------------------------------------------------------------------
// K3: out = relu(VW0 + sum_{kt<4} partial[kt]), 8 elems/thread
// ---------------------------------------------------------------------------
__global__ __launch_bounds__(256)
void k3_reduce(const unsigned short* __restrict__ part, const float* __restrict__ VW0,
               float* __restrict__ out)
{
  const size_t i8 = ((size_t)blockIdx.x*256 + threadIdx.x)*8;
  f32x4 s0 = *(const f32x4*)(VW0 + i8);
  f32x4 s1 = *(const f32x4*)(VW0 + i8 + 4);
#pragma unroll
  for (int q=0;q<4;q++) {
    u32x4 u = *(const u32x4*)(part + (size_t)q*2097152u + i8);
    s0[0] += __uint_as_float(u[0] << 16);  s0[1] += __uint_as_float(u[0] & 0xffff0000u);
    s0[2] += __uint_as_float(u[1] << 16);  s0[3] += __uint_as_float(u[1] & 0xffff0000u);
    s1[0] += __uint_as_float(u[2] << 16);  s1[1] += __uint_as_float(u[2] & 0xffff0000u);
    s1[2] += __uint_as_float(u[3] << 16);  s1[3] += __uint_as_float(u[3] & 0xffff0000u);
  }
#pragma unroll
  for (int e=0;e<4;e++){ s0[e] = fmaxf(s0[e],0.f); s1[e] = fmaxf(s1[e],0.f); }
  *(f32x4*)(out + i8)     = s0;
  *(f32x4*)(out + i8 + 4) = s1;
}

// ---------------------------------------------------------------------------
extern "C" void kernel_launch(void* const* d_in, const int* in_sizes, int n_in,
                              void* d_out, int out_size, void* d_ws, size_t ws_size,
                              hipStream_t stream) {
  const float* Vg = (const float*)d_in[0];   // (8,1024,256) f32
  const float* Ag = (const float*)d_in[1];   // (8,1024,1024,4) f32
  const float* Hg = (const float*)d_in[2];   // (5,256,256) f32
  float* out = (float*)d_out;                // (8,1024,256) f32

  // ws: W2t bf16 16MB | VW0 f32 8MB | partials bf16 16MB = 40MB
  if (ws_size < 41943040u) return;
  char* ws = (char*)d_ws;
  unsigned short* W2t  = (unsigned short*)(ws);
  float*          VW0  = (float*)(ws + 16777216u);
  unsigned short* part = (unsigned short*)(ws + 16777216u + 8388608u);

  k1_vw    <<<dim3(256),  dim3(512), 0, stream>>>(Vg, Hg, W2t, VW0);
  k2_gemm  <<<dim3(256),  dim3(512), 0, stream>>>(Ag, W2t, part);
  k3_reduce<<<dim3(1024), dim3(256), 0, stream>>>(part, VW0, out);
}